// Round 4
// baseline (141.215 us; speedup 1.0000x reference)
//
#include <hip/hip_runtime.h>

typedef float f4 __attribute__((ext_vector_type(4)));  // native vector for nt ld/st

// Problem constants
constexpr int Bn = 16;
constexpr int Sn = 8192;
constexpr int Dn = 256;             // D_MODEL = K_CH = OUT = 256
constexpr float kScale = 0.0625f;   // 1/sqrt(256)
constexpr int NCHUNK = 64;          // s-chunks per batch
constexpr int CHUNK  = Sn / NCHUNK; // 128 rows per chunk

// Workspace layout (float offsets); ~266k floats ≈ 1.07 MB
constexpr int M_OFF    = 0;                     // chunk max   [B][NCHUNK]
constexpr int SUM_OFF  = M_OFF + Bn * NCHUNK;   // chunk expsum[B][NCHUNK]
constexpr int PART_OFF = SUM_OFF + Bn * NCHUNK; // partials    [B][NCHUNK][D]

// ---------------------------------------------------------------------------
// K1: per (batch, chunk) block:
//   (a) redundant tiny GEMVs: q = query@Wq+bq ; r = Wk@q ; c = q.bk   (L2 data)
//   (b) scores -> chunk-local softmax -> weighted V partial           (HBM stream)
// grid = B * NCHUNK = 1024 blocks, 256 threads (4 waves)
__global__ __launch_bounds__(256) void k_fused(
    const float* __restrict__ query, const float* __restrict__ Wq,
    const float* __restrict__ bq, const float* __restrict__ Wk,
    const float* __restrict__ bk,
    const float* __restrict__ key, const float* __restrict__ value,
    float* __restrict__ ws) {
  int blk = blockIdx.x;
  int b = blk >> 6;        // / NCHUNK
  int chunk = blk & 63;
  int s0 = chunk * CHUNK;
  int t = threadIdx.x, lane = t & 63, wv = t >> 6;

  __shared__ float qs[Dn];      // input query row
  __shared__ float qh[Dn];      // projected q
  __shared__ float rsh[Dn];     // r = Wk @ q
  __shared__ float sc[CHUNK];   // raw scores
  __shared__ float wsh[CHUNK];  // exp(s - m_c)
  __shared__ float red[4][Dn];  // reductions (flat 1024 floats)
  float* redf = &red[0][0];

  // ---- (a) redundant qrc (weights are L2-resident after first touch) ----
  qs[t] = query[b * Dn + t];
  __syncthreads();
  float acc = bq[t];
  #pragma unroll 8
  for (int d = 0; d < Dn; ++d) acc += qs[d] * Wq[d * Dn + t];  // coalesced over t
  qh[t] = acc;
  __syncthreads();
  float racc = 0.f;
  #pragma unroll 8
  for (int o = 0; o < Dn; ++o) racc += Wk[t * Dn + o] * qh[o];
  rsh[t] = racc;
  redf[t] = qh[t] * bk[t];
  __syncthreads();
  for (int off = 128; off; off >>= 1) {
    if (t < off) redf[t] += redf[t + off];
    __syncthreads();
  }
  float cb = redf[0];
  __syncthreads();
  f4 rv = ((const f4*)rsh)[lane];  // one-time LDS read, reused 32x

  const f4* kp = (const f4*)(key + ((size_t)b * Sn + s0) * Dn);
  const f4* vp = (const f4*)(value + ((size_t)b * Sn + s0) * Dn);

  // ---- (b) Phase 1: scores for 128 rows (wave per row, 1 KiB coalesced) ----
  #pragma unroll 4
  for (int i = 0; i < CHUNK / 4; ++i) {
    int sl = wv + 4 * i;
    f4 kv = __builtin_nontemporal_load(&kp[(size_t)sl * 64 + lane]);
    float dot = kv.x * rv.x + kv.y * rv.y + kv.z * rv.z + kv.w * rv.w;
    #pragma unroll
    for (int off = 32; off; off >>= 1) dot += __shfl_xor(dot, off, 64);
    if (lane == 0) sc[sl] = (dot + cb) * kScale;
  }
  __syncthreads();

  // Chunk-local max (uniform broadcast reads)
  float m = -1e30f;
  #pragma unroll 8
  for (int i = 0; i < CHUNK; ++i) m = fmaxf(m, sc[i]);
  if (t < CHUNK) wsh[t] = __expf(sc[t] - m);
  __syncthreads();

  // Phase 2: weighted value partial
  f4 vacc = {0.f, 0.f, 0.f, 0.f};
  #pragma unroll 4
  for (int i = 0; i < CHUNK / 4; ++i) {
    int sl = wv + 4 * i;
    f4 v = __builtin_nontemporal_load(&vp[(size_t)sl * 64 + lane]);
    float w = wsh[sl];
    vacc.x += w * v.x; vacc.y += w * v.y; vacc.z += w * v.z; vacc.w += w * v.w;
  }
  red[wv][lane * 4 + 0] = vacc.x;
  red[wv][lane * 4 + 1] = vacc.y;
  red[wv][lane * 4 + 2] = vacc.z;
  red[wv][lane * 4 + 3] = vacc.w;
  __syncthreads();
  float part = red[0][t] + red[1][t] + red[2][t] + red[3][t];
  ws[PART_OFF + ((size_t)b * NCHUNK + chunk) * Dn + t] = part;
  if (t == 0) {
    float ssum = 0.f;
    #pragma unroll 8
    for (int i = 0; i < CHUNK; ++i) ssum += wsh[i];
    ws[M_OFF + b * NCHUNK + chunk] = m;
    ws[SUM_OFF + b * NCHUNK + chunk] = ssum;
  }
}

// ---------------------------------------------------------------------------
// K2: per (batch, chunk) block:
//   (a) redundant LSE combine over 64 chunks -> ctx = (u/denom)@Wv + bv  (L2)
//   (b) nt-write ctx broadcast to out[b][s0..s0+127][:]                  (HBM)
// grid = B * NCHUNK = 1024 blocks, 256 threads
__global__ __launch_bounds__(256) void k_out(
    const float* __restrict__ Wv, const float* __restrict__ bv,
    const float* __restrict__ ws, float* __restrict__ out) {
  int blk = blockIdx.x;
  int b = blk >> 6;
  int chunk = blk & 63;
  int s0 = chunk * CHUNK;
  int t = threadIdx.x, lane = t & 63, wv = t >> 6;

  __shared__ float msh[NCHUNK];
  __shared__ float e[NCHUNK];
  __shared__ float ush[Dn];
  __shared__ float ctx[Dn];

  if (t < NCHUNK) msh[t] = ws[M_OFF + b * NCHUNK + t];
  __syncthreads();
  float gm = -1e30f;
  #pragma unroll 8
  for (int c = 0; c < NCHUNK; ++c) gm = fmaxf(gm, msh[c]);
  if (t < NCHUNK) e[t] = __expf(msh[t] - gm);
  __syncthreads();
  float denom = 0.f;
  #pragma unroll 8
  for (int c = 0; c < NCHUNK; ++c) denom += ws[SUM_OFF + b * NCHUNK + c] * e[c];
  float u = 0.f;
  #pragma unroll 8
  for (int c = 0; c < NCHUNK; ++c)
    u += ws[PART_OFF + ((size_t)b * NCHUNK + c) * Dn + t] * e[c];  // coalesced
  ush[t] = u / denom;
  __syncthreads();
  float acc = bv[t];
  #pragma unroll 8
  for (int o = 0; o < Dn; ++o) acc += ush[o] * Wv[o * Dn + t];  // coalesced over t
  ctx[t] = acc;
  __syncthreads();

  f4 val = ((const f4*)ctx)[lane];
  f4* op = (f4*)(out + ((size_t)b * Sn + s0) * Dn);
  #pragma unroll 8
  for (int it = 0; it < CHUNK / 4; ++it) {
    int sl = wv + 4 * it;
    __builtin_nontemporal_store(val, &op[(size_t)sl * 64 + lane]);
  }
}

// ---------------------------------------------------------------------------
extern "C" void kernel_launch(void* const* d_in, const int* in_sizes, int n_in,
                              void* d_out, int out_size, void* d_ws, size_t ws_size,
                              hipStream_t stream) {
  const float* query = (const float*)d_in[0];
  const float* key   = (const float*)d_in[1];
  const float* value = (const float*)d_in[2];
  const float* Wq    = (const float*)d_in[3];
  const float* bq    = (const float*)d_in[4];
  const float* Wk    = (const float*)d_in[5];
  const float* bk    = (const float*)d_in[6];
  const float* Wv    = (const float*)d_in[7];
  const float* bv    = (const float*)d_in[8];
  float* out = (float*)d_out;
  float* ws  = (float*)d_ws;

  hipLaunchKernelGGL(k_fused, dim3(Bn * NCHUNK), dim3(256), 0, stream,
                     query, Wq, bq, Wk, bk, key, value, ws);
  hipLaunchKernelGGL(k_out,   dim3(Bn * NCHUNK), dim3(256), 0, stream,
                     Wv, bv, ws, out);
}

// Round 5
// 102.598 us; speedup vs baseline: 1.3764x; 1.3764x over previous
//
#include <hip/hip_runtime.h>

typedef float f4 __attribute__((ext_vector_type(4)));  // native vector for nt ld/st

// Problem constants
constexpr int Bn = 16;
constexpr int Sn = 8192;
constexpr int Dn = 256;             // D_MODEL = K_CH = OUT = 256
constexpr float kScale = 0.0625f;   // 1/sqrt(256)
constexpr int NCHUNK = 64;          // s-chunks per batch
constexpr int CHUNK  = Sn / NCHUNK; // 128 rows per chunk

// Workspace layout (float offsets); ~271k floats ≈ 1.08 MB
constexpr int R_OFF    = 0;                     // r[B][D] = Wk @ q
constexpr int C_OFF    = R_OFF + Bn * Dn;       // c[B]    = q . bk
constexpr int M_OFF    = C_OFF + 64;            // chunk max   [B][NCHUNK]
constexpr int SUM_OFF  = M_OFF + Bn * NCHUNK;   // chunk expsum[B][NCHUNK]
constexpr int PART_OFF = SUM_OFF + Bn * NCHUNK; // partials    [B][NCHUNK][D]

// ---------------------------------------------------------------------------
// K1: per-batch tiny GEMVs: q = query@Wq + bq ; r = Wk@q ; c = q.bk
// 16 blocks — latency-bound, so deep unrolls + f4 row reads to maximize
// loads in flight (cold-HBM latency ~375 ns; 8 rounds ≈ 3 µs).
__global__ __launch_bounds__(256) void k_qrc(
    const float* __restrict__ query, const float* __restrict__ Wq,
    const float* __restrict__ bq, const float* __restrict__ Wk,
    const float* __restrict__ bk, float* __restrict__ ws) {
  int b = blockIdx.x, t = threadIdx.x;
  __shared__ float qs[Dn];
  __shared__ float qh[Dn];
  __shared__ float red[256];
  qs[t] = query[b * Dn + t];
  __syncthreads();
  float acc = bq[t];
  #pragma unroll 32
  for (int d = 0; d < Dn; ++d) acc += qs[d] * Wq[d * Dn + t];  // coalesced over t
  qh[t] = acc;
  __syncthreads();
  // r[t] = Wk[t,:] . qh  — per-thread contiguous row, f4 loads, 16 in flight
  float racc = 0.f;
  const f4* wkrow = (const f4*)(Wk + (size_t)t * Dn);
  const f4* qh4 = (const f4*)qh;
  #pragma unroll 16
  for (int o4 = 0; o4 < Dn / 4; ++o4) {
    f4 wv = wkrow[o4];
    f4 qv = qh4[o4];  // uniform address -> LDS broadcast, conflict-free
    racc += wv.x * qv.x + wv.y * qv.y + wv.z * qv.z + wv.w * qv.w;
  }
  ws[R_OFF + b * Dn + t] = racc;
  red[t] = qh[t] * bk[t];
  __syncthreads();
  for (int off = 128; off; off >>= 1) {
    if (t < off) red[t] += red[t + off];
    __syncthreads();
  }
  if (t == 0) ws[C_OFF + b] = red[0];
}

// ---------------------------------------------------------------------------
// K2 (streaming): per (batch, chunk): scores -> chunk-local softmax -> weighted
// V partial. Reads key chunk + value chunk (128 KiB each) exactly once, nt.
// grid = B * NCHUNK = 1024 blocks, 256 threads (4 waves)
__global__ __launch_bounds__(256) void k_fused(
    const float* __restrict__ key, const float* __restrict__ value,
    float* __restrict__ ws) {
  int blk = blockIdx.x;
  int b = blk >> 6;        // / NCHUNK
  int chunk = blk & 63;
  int s0 = chunk * CHUNK;
  int t = threadIdx.x, lane = t & 63, wv = t >> 6;
  __shared__ float sc[CHUNK];   // raw scores
  __shared__ float wsh[CHUNK];  // exp(s - m_c)
  __shared__ float red[4][Dn];

  f4 rv = ((const f4*)(ws + R_OFF + b * Dn))[lane];
  float cb = ws[C_OFF + b];
  const f4* kp = (const f4*)(key + ((size_t)b * Sn + s0) * Dn);
  const f4* vp = (const f4*)(value + ((size_t)b * Sn + s0) * Dn);

  // Phase 1: scores for 128 rows (wave per row, 1 KiB coalesced per row)
  #pragma unroll 4
  for (int i = 0; i < CHUNK / 4; ++i) {
    int sl = wv + 4 * i;
    f4 kv = __builtin_nontemporal_load(&kp[(size_t)sl * 64 + lane]);
    float dot = kv.x * rv.x + kv.y * rv.y + kv.z * rv.z + kv.w * rv.w;
    #pragma unroll
    for (int off = 32; off; off >>= 1) dot += __shfl_xor(dot, off, 64);
    if (lane == 0) sc[sl] = (dot + cb) * kScale;
  }
  __syncthreads();

  // Chunk-local max (uniform broadcast reads)
  float m = -1e30f;
  #pragma unroll 8
  for (int i = 0; i < CHUNK; ++i) m = fmaxf(m, sc[i]);
  if (t < CHUNK) wsh[t] = __expf(sc[t] - m);
  __syncthreads();

  // Phase 2: weighted value partial
  f4 vacc = {0.f, 0.f, 0.f, 0.f};
  #pragma unroll 4
  for (int i = 0; i < CHUNK / 4; ++i) {
    int sl = wv + 4 * i;
    f4 v = __builtin_nontemporal_load(&vp[(size_t)sl * 64 + lane]);
    float w = wsh[sl];
    vacc.x += w * v.x; vacc.y += w * v.y; vacc.z += w * v.z; vacc.w += w * v.w;
  }
  red[wv][lane * 4 + 0] = vacc.x;
  red[wv][lane * 4 + 1] = vacc.y;
  red[wv][lane * 4 + 2] = vacc.z;
  red[wv][lane * 4 + 3] = vacc.w;
  __syncthreads();
  float part = red[0][t] + red[1][t] + red[2][t] + red[3][t];
  ws[PART_OFF + ((size_t)b * NCHUNK + chunk) * Dn + t] = part;
  if (t == 0) {
    float ssum = 0.f;
    #pragma unroll 8
    for (int i = 0; i < CHUNK; ++i) ssum += wsh[i];
    ws[M_OFF + b * NCHUNK + chunk] = m;
    ws[SUM_OFF + b * NCHUNK + chunk] = ssum;
  }
}

// ---------------------------------------------------------------------------
// K3: per (batch, chunk) block: redundant LSE combine (all loads coalesced,
// L2-resident: partials 1 MB + Wv 256 KB) -> ctx, then nt-write 128 rows.
// grid = B * NCHUNK = 1024 blocks, 256 threads
__global__ __launch_bounds__(256) void k_out(
    const float* __restrict__ Wv, const float* __restrict__ bv,
    const float* __restrict__ ws, float* __restrict__ out) {
  int blk = blockIdx.x;
  int b = blk >> 6;
  int chunk = blk & 63;
  int s0 = chunk * CHUNK;
  int t = threadIdx.x, lane = t & 63, wv = t >> 6;

  __shared__ float msh[NCHUNK];
  __shared__ float e[NCHUNK];
  __shared__ float ush[Dn];
  __shared__ float ctx[Dn];

  if (t < NCHUNK) msh[t] = ws[M_OFF + b * NCHUNK + t];
  __syncthreads();
  float gm = -1e30f;
  #pragma unroll 16
  for (int c = 0; c < NCHUNK; ++c) gm = fmaxf(gm, msh[c]);
  if (t < NCHUNK) e[t] = __expf(msh[t] - gm);
  __syncthreads();
  float denom = 0.f;
  #pragma unroll 16
  for (int c = 0; c < NCHUNK; ++c) denom += ws[SUM_OFF + b * NCHUNK + c] * e[c];
  float u = 0.f;
  #pragma unroll 16
  for (int c = 0; c < NCHUNK; ++c)
    u += ws[PART_OFF + ((size_t)b * NCHUNK + c) * Dn + t] * e[c];  // coalesced
  ush[t] = u / denom;
  __syncthreads();
  float acc = bv[t];
  #pragma unroll 16
  for (int o = 0; o < Dn; ++o) acc += ush[o] * Wv[o * Dn + t];  // coalesced over t
  ctx[t] = acc;
  __syncthreads();

  f4 val = ((const f4*)ctx)[lane];
  f4* op = (f4*)(out + ((size_t)b * Sn + s0) * Dn);
  #pragma unroll 8
  for (int it = 0; it < CHUNK / 4; ++it) {
    int sl = wv + 4 * it;
    __builtin_nontemporal_store(val, &op[(size_t)sl * 64 + lane]);
  }
}

// ---------------------------------------------------------------------------
extern "C" void kernel_launch(void* const* d_in, const int* in_sizes, int n_in,
                              void* d_out, int out_size, void* d_ws, size_t ws_size,
                              hipStream_t stream) {
  const float* query = (const float*)d_in[0];
  const float* key   = (const float*)d_in[1];
  const float* value = (const float*)d_in[2];
  const float* Wq    = (const float*)d_in[3];
  const float* bq    = (const float*)d_in[4];
  const float* Wk    = (const float*)d_in[5];
  const float* bk    = (const float*)d_in[6];
  const float* Wv    = (const float*)d_in[7];
  const float* bv    = (const float*)d_in[8];
  float* out = (float*)d_out;
  float* ws  = (float*)d_ws;

  hipLaunchKernelGGL(k_qrc,   dim3(Bn),          dim3(256), 0, stream,
                     query, Wq, bq, Wk, bk, ws);
  hipLaunchKernelGGL(k_fused, dim3(Bn * NCHUNK), dim3(256), 0, stream,
                     key, value, ws);
  hipLaunchKernelGGL(k_out,   dim3(Bn * NCHUNK), dim3(256), 0, stream,
                     Wv, bv, ws, out);
}

// Round 6
// 100.153 us; speedup vs baseline: 1.4100x; 1.0244x over previous
//
#include <hip/hip_runtime.h>

typedef float f4 __attribute__((ext_vector_type(4)));  // native vector for nt ld/st

// Problem constants
constexpr int Bn = 16;
constexpr int Sn = 8192;
constexpr int Dn = 256;             // D_MODEL = K_CH = OUT = 256
constexpr float kScale = 0.0625f;   // 1/sqrt(256)
constexpr int NCHUNK = 128;         // score/V chunks per batch (64 rows each)
constexpr int CHUNK  = Sn / NCHUNK; // 64 rows per fused block
constexpr int OROWS  = 128;         // output rows per k_out block

// Workspace layout (float offsets); ~530k floats = 2.1 MB
constexpr int R_OFF    = 0;                     // r[B][D] = Wk @ q
constexpr int C_OFF    = R_OFF + Bn * Dn;       // c[B]    = q . bk
constexpr int M_OFF    = C_OFF + 64;            // chunk max   [B][NCHUNK]
constexpr int SUM_OFF  = M_OFF + Bn * NCHUNK;   // chunk expsum[B][NCHUNK]
constexpr int PART_OFF = SUM_OFF + Bn * NCHUNK; // partials    [B][NCHUNK][D]

// ---------------------------------------------------------------------------
// K1: per-batch tiny GEMVs: q = query@Wq + bq ; r = Wk@q ; c = q.bk
__global__ __launch_bounds__(256) void k_qrc(
    const float* __restrict__ query, const float* __restrict__ Wq,
    const float* __restrict__ bq, const float* __restrict__ Wk,
    const float* __restrict__ bk, float* __restrict__ ws) {
  int b = blockIdx.x, t = threadIdx.x;
  __shared__ float qs[Dn];
  __shared__ float qh[Dn];
  __shared__ float red[256];
  qs[t] = query[b * Dn + t];
  __syncthreads();
  float acc = bq[t];
  #pragma unroll 32
  for (int d = 0; d < Dn; ++d) acc += qs[d] * Wq[d * Dn + t];  // coalesced over t
  qh[t] = acc;
  __syncthreads();
  float racc = 0.f;
  const f4* wkrow = (const f4*)(Wk + (size_t)t * Dn);
  const f4* qh4 = (const f4*)qh;
  #pragma unroll 16
  for (int o4 = 0; o4 < Dn / 4; ++o4) {
    f4 wv = wkrow[o4];
    f4 qv = qh4[o4];
    racc += wv.x * qv.x + wv.y * qv.y + wv.z * qv.z + wv.w * qv.w;
  }
  ws[R_OFF + b * Dn + t] = racc;
  red[t] = qh[t] * bk[t];
  __syncthreads();
  for (int off = 128; off; off >>= 1) {
    if (t < off) red[t] += red[t + off];
    __syncthreads();
  }
  if (t == 0) ws[C_OFF + b] = red[0];
}

// ---------------------------------------------------------------------------
// K2 (single-pass online softmax): per (batch, 64-row chunk):
// each wave streams K-row + V-row together, butterfly-reduces the score
// (all lanes get it -> wave-uniform rescale branch), updates running
// (m, sum, vacc) in registers. One barrier at the end for 4-wave combine.
// grid = B * NCHUNK = 2048 blocks, 256 threads -> 8 blocks/CU, 32 waves/CU
__global__ __launch_bounds__(256) void k_fused(
    const float* __restrict__ key, const float* __restrict__ value,
    float* __restrict__ ws) {
  int blk = blockIdx.x;
  int b = blk >> 7;         // / NCHUNK
  int chunk = blk & 127;
  int s0 = chunk * CHUNK;
  int t = threadIdx.x, lane = t & 63, wv = t >> 6;

  __shared__ float wm[4], wsum[4];
  __shared__ f4 wva[4][64];   // per-wave vacc (4 KB)

  f4 rv = ((const f4*)(ws + R_OFF + b * Dn))[lane];
  float cb = ws[C_OFF + b];
  const f4* kp = (const f4*)(key + ((size_t)b * Sn + s0) * Dn);
  const f4* vp = (const f4*)(value + ((size_t)b * Sn + s0) * Dn);

  float m = -1e30f, sum = 0.f;
  f4 vacc = {0.f, 0.f, 0.f, 0.f};

  #pragma unroll 4
  for (int i = 0; i < CHUNK / 4; ++i) {   // 16 rows per wave
    int sl = wv + 4 * i;
    f4 kv = __builtin_nontemporal_load(&kp[(size_t)sl * 64 + lane]);
    f4 vv = __builtin_nontemporal_load(&vp[(size_t)sl * 64 + lane]);
    float dot = kv.x * rv.x + kv.y * rv.y + kv.z * rv.z + kv.w * rv.w;
    #pragma unroll
    for (int off = 32; off; off >>= 1) dot += __shfl_xor(dot, off, 64);
    float s = (dot + cb) * kScale;        // identical in all 64 lanes
    if (s > m) {                          // wave-uniform, rare after warmup
      float sc = __expf(m - s);
      sum *= sc;
      vacc *= sc;
      m = s;
    }
    float w = __expf(s - m);
    sum += w;
    vacc += w * vv;
  }

  if (lane == 0) { wm[wv] = m; wsum[wv] = sum; }
  wva[wv][lane] = vacc;
  __syncthreads();

  float gm = fmaxf(fmaxf(wm[0], wm[1]), fmaxf(wm[2], wm[3]));
  float e0 = __expf(wm[0] - gm), e1 = __expf(wm[1] - gm);
  float e2 = __expf(wm[2] - gm), e3 = __expf(wm[3] - gm);
  const float* v0 = (const float*)&wva[0][0];
  const float* v1 = (const float*)&wva[1][0];
  const float* v2 = (const float*)&wva[2][0];
  const float* v3 = (const float*)&wva[3][0];
  float part = v0[t] * e0 + v1[t] * e1 + v2[t] * e2 + v3[t] * e3;
  ws[PART_OFF + ((size_t)b * NCHUNK + chunk) * Dn + t] = part;
  if (t == 0) {
    ws[M_OFF + b * NCHUNK + chunk] = gm;
    ws[SUM_OFF + b * NCHUNK + chunk] =
        wsum[0] * e0 + wsum[1] * e1 + wsum[2] * e2 + wsum[3] * e3;
  }
}

// ---------------------------------------------------------------------------
// K3: per (batch, 128-row slice): redundant LSE combine over 128 chunks
// (L2-resident) -> ctx = (u/denom)@Wv + bv, then nt-write 128 output rows.
// grid = B * Sn/OROWS = 1024 blocks, 256 threads
__global__ __launch_bounds__(256) void k_out(
    const float* __restrict__ Wv, const float* __restrict__ bv,
    const float* __restrict__ ws, float* __restrict__ out) {
  int blk = blockIdx.x;
  int b = blk >> 6;          // 64 slices per batch
  int oc = blk & 63;
  int s0 = oc * OROWS;
  int t = threadIdx.x, lane = t & 63, wv = t >> 6;

  __shared__ float msh[NCHUNK];
  __shared__ float ssh[NCHUNK];
  __shared__ float e[NCHUNK];
  __shared__ float ush[Dn];
  __shared__ float ctx[Dn];

  if (t < NCHUNK) msh[t] = ws[M_OFF + b * NCHUNK + t];
  else            ssh[t - NCHUNK] = ws[SUM_OFF + b * NCHUNK + (t - NCHUNK)];
  __syncthreads();
  float gm = -1e30f;
  #pragma unroll 16
  for (int c = 0; c < NCHUNK; ++c) gm = fmaxf(gm, msh[c]);
  if (t < NCHUNK) e[t] = __expf(msh[t] - gm);
  __syncthreads();
  float denom = 0.f;
  #pragma unroll 16
  for (int c = 0; c < NCHUNK; ++c) denom += ssh[c] * e[c];
  float u = 0.f;
  #pragma unroll 16
  for (int c = 0; c < NCHUNK; ++c)
    u += ws[PART_OFF + ((size_t)b * NCHUNK + c) * Dn + t] * e[c];  // coalesced
  ush[t] = u / denom;
  __syncthreads();
  float acc = bv[t];
  #pragma unroll 16
  for (int o = 0; o < Dn; ++o) acc += ush[o] * Wv[o * Dn + t];  // coalesced
  ctx[t] = acc;
  __syncthreads();

  f4 val = ((const f4*)ctx)[lane];
  f4* op = (f4*)(out + ((size_t)b * Sn + s0) * Dn);
  #pragma unroll 8
  for (int it = 0; it < OROWS / 4; ++it) {
    int sl = wv + 4 * it;
    __builtin_nontemporal_store(val, &op[(size_t)sl * 64 + lane]);
  }
}

// ---------------------------------------------------------------------------
extern "C" void kernel_launch(void* const* d_in, const int* in_sizes, int n_in,
                              void* d_out, int out_size, void* d_ws, size_t ws_size,
                              hipStream_t stream) {
  const float* query = (const float*)d_in[0];
  const float* key   = (const float*)d_in[1];
  const float* value = (const float*)d_in[2];
  const float* Wq    = (const float*)d_in[3];
  const float* bq    = (const float*)d_in[4];
  const float* Wk    = (const float*)d_in[5];
  const float* bk    = (const float*)d_in[6];
  const float* Wv    = (const float*)d_in[7];
  const float* bv    = (const float*)d_in[8];
  float* out = (float*)d_out;
  float* ws  = (float*)d_ws;

  hipLaunchKernelGGL(k_qrc,   dim3(Bn),          dim3(256), 0, stream,
                     query, Wq, bq, Wk, bk, ws);
  hipLaunchKernelGGL(k_fused, dim3(Bn * NCHUNK), dim3(256), 0, stream,
                     key, value, ws);
  hipLaunchKernelGGL(k_out,   dim3(Bn * 64),     dim3(256), 0, stream,
                     Wv, bv, ws, out);
}

// Round 7
// 99.056 us; speedup vs baseline: 1.4256x; 1.0111x over previous
//
#include <hip/hip_runtime.h>

typedef float f4 __attribute__((ext_vector_type(4)));  // native vector for nt ld/st

// Problem constants
constexpr int Bn = 16;
constexpr int Sn = 8192;
constexpr int Dn = 256;             // D_MODEL = K_CH = OUT = 256
constexpr float kScale = 0.0625f;   // 1/sqrt(256)
constexpr int NCHUNK = 128;         // score/V chunks per batch (64 rows each)
constexpr int CHUNK  = Sn / NCHUNK; // 64 rows per fused block
constexpr int OROWS  = 128;         // output rows per k_out block

// Workspace layout (float offsets); ~530k floats = 2.1 MB
constexpr int R_OFF    = 0;                     // r[B][D] = Wk @ q
constexpr int C_OFF    = R_OFF + Bn * Dn;       // c[B]    = q . bk
constexpr int M_OFF    = C_OFF + 64;            // chunk max   [B][NCHUNK]
constexpr int SUM_OFF  = M_OFF + Bn * NCHUNK;   // chunk expsum[B][NCHUNK]
constexpr int PART_OFF = SUM_OFF + Bn * NCHUNK; // partials    [B][NCHUNK][D]

// ---------------------------------------------------------------------------
// K1: per-batch tiny GEMVs: q = query@Wq + bq ; r = Wk@q ; c = q.bk
// (unchanged from round 6)
__global__ __launch_bounds__(256) void k_qrc(
    const float* __restrict__ query, const float* __restrict__ Wq,
    const float* __restrict__ bq, const float* __restrict__ Wk,
    const float* __restrict__ bk, float* __restrict__ ws) {
  int b = blockIdx.x, t = threadIdx.x;
  __shared__ float qs[Dn];
  __shared__ float qh[Dn];
  __shared__ float red[256];
  qs[t] = query[b * Dn + t];
  __syncthreads();
  float acc = bq[t];
  #pragma unroll 32
  for (int d = 0; d < Dn; ++d) acc += qs[d] * Wq[d * Dn + t];  // coalesced over t
  qh[t] = acc;
  __syncthreads();
  float racc = 0.f;
  const f4* wkrow = (const f4*)(Wk + (size_t)t * Dn);
  const f4* qh4 = (const f4*)qh;
  #pragma unroll 16
  for (int o4 = 0; o4 < Dn / 4; ++o4) {
    f4 wv = wkrow[o4];
    f4 qv = qh4[o4];
    racc += wv.x * qv.x + wv.y * qv.y + wv.z * qv.z + wv.w * qv.w;
  }
  ws[R_OFF + b * Dn + t] = racc;
  red[t] = qh[t] * bk[t];
  __syncthreads();
  for (int off = 128; off; off >>= 1) {
    if (t < off) red[t] += red[t + off];
    __syncthreads();
  }
  if (t == 0) ws[C_OFF + b] = red[0];
}

// ---------------------------------------------------------------------------
// K2 (single-pass online softmax, software-pipelined):
// per (batch, 64-row chunk); each wave streams K-row + V-row together with a
// 1-iteration-deep manual pipeline (plain cached loads, NO nt), butterfly
// score, wave-uniform rescale, running (m,sum,vacc) in registers.
// grid = B * NCHUNK = 2048 blocks, 256 threads
__global__ __launch_bounds__(256) void k_fused(
    const float* __restrict__ key, const float* __restrict__ value,
    float* __restrict__ ws) {
  int blk = blockIdx.x;
  int b = blk >> 7;         // / NCHUNK
  int chunk = blk & 127;
  int s0 = chunk * CHUNK;
  int t = threadIdx.x, lane = t & 63, wv = t >> 6;

  __shared__ float wm[4], wsum[4];
  __shared__ f4 wva[4][64];   // per-wave vacc (4 KB)

  f4 rv = ((const f4*)(ws + R_OFF + b * Dn))[lane];
  float cb = ws[C_OFF + b];
  const f4* kp = (const f4*)(key + ((size_t)b * Sn + s0) * Dn);
  const f4* vp = (const f4*)(value + ((size_t)b * Sn + s0) * Dn);

  float m = -1e30f, sum = 0.f;
  f4 vacc = {0.f, 0.f, 0.f, 0.f};

  // Prologue: load row-pair for iteration 0 (row = wv)
  f4 kv = kp[(size_t)wv * 64 + lane];
  f4 vv = vp[(size_t)wv * 64 + lane];

  #pragma unroll
  for (int i = 0; i < CHUNK / 4; ++i) {   // 16 rows per wave
    f4 kn, vn;
    if (i + 1 < CHUNK / 4) {              // issue next loads BEFORE the
      int sn = wv + 4 * (i + 1);          // ~250-cycle shuffle/exp chain
      kn = kp[(size_t)sn * 64 + lane];
      vn = vp[(size_t)sn * 64 + lane];
    }
    float dot = kv.x * rv.x + kv.y * rv.y + kv.z * rv.z + kv.w * rv.w;
    #pragma unroll
    for (int off = 32; off; off >>= 1) dot += __shfl_xor(dot, off, 64);
    float s = (dot + cb) * kScale;        // identical in all 64 lanes
    if (s > m) {                          // wave-uniform, rare after warmup
      float sc = __expf(m - s);
      sum *= sc;
      vacc *= sc;
      m = s;
    }
    float w = __expf(s - m);
    sum += w;
    vacc += w * vv;
    kv = kn; vv = vn;
  }

  if (lane == 0) { wm[wv] = m; wsum[wv] = sum; }
  wva[wv][lane] = vacc;
  __syncthreads();

  float gm = fmaxf(fmaxf(wm[0], wm[1]), fmaxf(wm[2], wm[3]));
  float e0 = __expf(wm[0] - gm), e1 = __expf(wm[1] - gm);
  float e2 = __expf(wm[2] - gm), e3 = __expf(wm[3] - gm);
  const float* v0 = (const float*)&wva[0][0];
  const float* v1 = (const float*)&wva[1][0];
  const float* v2 = (const float*)&wva[2][0];
  const float* v3 = (const float*)&wva[3][0];
  float part = v0[t] * e0 + v1[t] * e1 + v2[t] * e2 + v3[t] * e3;
  ws[PART_OFF + ((size_t)b * NCHUNK + chunk) * Dn + t] = part;
  if (t == 0) {
    ws[M_OFF + b * NCHUNK + chunk] = gm;
    ws[SUM_OFF + b * NCHUNK + chunk] =
        wsum[0] * e0 + wsum[1] * e1 + wsum[2] * e2 + wsum[3] * e3;
  }
}

// ---------------------------------------------------------------------------
// K3: per (batch, 128-row slice): redundant LSE combine over 128 chunks
// (L2-resident) -> ctx = (u/denom)@Wv + bv, then nt-write 128 output rows.
// (unchanged from round 6)
__global__ __launch_bounds__(256) void k_out(
    const float* __restrict__ Wv, const float* __restrict__ bv,
    const float* __restrict__ ws, float* __restrict__ out) {
  int blk = blockIdx.x;
  int b = blk >> 6;          // 64 slices per batch
  int oc = blk & 63;
  int s0 = oc * OROWS;
  int t = threadIdx.x, lane = t & 63, wv = t >> 6;

  __shared__ float msh[NCHUNK];
  __shared__ float ssh[NCHUNK];
  __shared__ float e[NCHUNK];
  __shared__ float ush[Dn];
  __shared__ float ctx[Dn];

  if (t < NCHUNK) msh[t] = ws[M_OFF + b * NCHUNK + t];
  else            ssh[t - NCHUNK] = ws[SUM_OFF + b * NCHUNK + (t - NCHUNK)];
  __syncthreads();
  float gm = -1e30f;
  #pragma unroll 16
  for (int c = 0; c < NCHUNK; ++c) gm = fmaxf(gm, msh[c]);
  if (t < NCHUNK) e[t] = __expf(msh[t] - gm);
  __syncthreads();
  float denom = 0.f;
  #pragma unroll 16
  for (int c = 0; c < NCHUNK; ++c) denom += ssh[c] * e[c];
  float u = 0.f;
  #pragma unroll 16
  for (int c = 0; c < NCHUNK; ++c)
    u += ws[PART_OFF + ((size_t)b * NCHUNK + c) * Dn + t] * e[c];  // coalesced
  ush[t] = u / denom;
  __syncthreads();
  float acc = bv[t];
  #pragma unroll 16
  for (int o = 0; o < Dn; ++o) acc += ush[o] * Wv[o * Dn + t];  // coalesced
  ctx[t] = acc;
  __syncthreads();

  f4 val = ((const f4*)ctx)[lane];
  f4* op = (f4*)(out + ((size_t)b * Sn + s0) * Dn);
  #pragma unroll 8
  for (int it = 0; it < OROWS / 4; ++it) {
    int sl = wv + 4 * it;
    __builtin_nontemporal_store(val, &op[(size_t)sl * 64 + lane]);
  }
}

// ---------------------------------------------------------------------------
extern "C" void kernel_launch(void* const* d_in, const int* in_sizes, int n_in,
                              void* d_out, int out_size, void* d_ws, size_t ws_size,
                              hipStream_t stream) {
  const float* query = (const float*)d_in[0];
  const float* key   = (const float*)d_in[1];
  const float* value = (const float*)d_in[2];
  const float* Wq    = (const float*)d_in[3];
  const float* bq    = (const float*)d_in[4];
  const float* Wk    = (const float*)d_in[5];
  const float* bk    = (const float*)d_in[6];
  const float* Wv    = (const float*)d_in[7];
  const float* bv    = (const float*)d_in[8];
  float* out = (float*)d_out;
  float* ws  = (float*)d_ws;

  hipLaunchKernelGGL(k_qrc,   dim3(Bn),          dim3(256), 0, stream,
                     query, Wq, bq, Wk, bk, ws);
  hipLaunchKernelGGL(k_fused, dim3(Bn * NCHUNK), dim3(256), 0, stream,
                     key, value, ws);
  hipLaunchKernelGGL(k_out,   dim3(Bn * 64),     dim3(256), 0, stream,
                     Wv, bv, ws, out);
}

// Round 8
// 98.361 us; speedup vs baseline: 1.4357x; 1.0071x over previous
//
#include <hip/hip_runtime.h>

typedef float f4 __attribute__((ext_vector_type(4)));  // native vector for nt ld/st

// Problem constants
constexpr int Bn = 16;
constexpr int Sn = 8192;
constexpr int Dn = 256;             // D_MODEL = K_CH = OUT = 256
constexpr float kScale = 0.0625f;   // 1/sqrt(256)
constexpr int NCHUNK = 128;         // score/V chunks per batch (64 rows each)
constexpr int CHUNK  = Sn / NCHUNK; // 64 rows per fused block
constexpr int OROWS  = 128;         // output rows per k_out block

// Workspace layout (float offsets); ~530k floats = 2.1 MB
constexpr int R_OFF    = 0;                     // r[B][D] = Wk @ q
constexpr int C_OFF    = R_OFF + Bn * Dn;       // c[B]    = q . bk
constexpr int M_OFF    = C_OFF + 64;            // chunk max   [B][NCHUNK]
constexpr int SUM_OFF  = M_OFF + Bn * NCHUNK;   // chunk expsum[B][NCHUNK]
constexpr int PART_OFF = SUM_OFF + Bn * NCHUNK; // partials    [B][NCHUNK][D]

// ---------------------------------------------------------------------------
// K1: per-batch tiny GEMVs: q = query@Wq + bq ; r = Wk@q ; c = q.bk
// (unchanged from round 6/7)
__global__ __launch_bounds__(256) void k_qrc(
    const float* __restrict__ query, const float* __restrict__ Wq,
    const float* __restrict__ bq, const float* __restrict__ Wk,
    const float* __restrict__ bk, float* __restrict__ ws) {
  int b = blockIdx.x, t = threadIdx.x;
  __shared__ float qs[Dn];
  __shared__ float qh[Dn];
  __shared__ float red[256];
  qs[t] = query[b * Dn + t];
  __syncthreads();
  float acc = bq[t];
  #pragma unroll 32
  for (int d = 0; d < Dn; ++d) acc += qs[d] * Wq[d * Dn + t];  // coalesced over t
  qh[t] = acc;
  __syncthreads();
  float racc = 0.f;
  const f4* wkrow = (const f4*)(Wk + (size_t)t * Dn);
  const f4* qh4 = (const f4*)qh;
  #pragma unroll 16
  for (int o4 = 0; o4 < Dn / 4; ++o4) {
    f4 wv = wkrow[o4];
    f4 qv = qh4[o4];
    racc += wv.x * qv.x + wv.y * qv.y + wv.z * qv.z + wv.w * qv.w;
  }
  ws[R_OFF + b * Dn + t] = racc;
  red[t] = qh[t] * bk[t];
  __syncthreads();
  for (int off = 128; off; off >>= 1) {
    if (t < off) red[t] += red[t + off];
    __syncthreads();
  }
  if (t == 0) ws[C_OFF + b] = red[0];
}

// ---------------------------------------------------------------------------
// K2 (online softmax, 4-row ILP): per (batch, 64-row chunk).
// Wave wv owns rows [wv*16, wv*16+16), processed as 4 groups of 4 rows:
// 8 f4 loads in flight (depth-1 group prefetch), 4 dots, one PACKED f4
// butterfly (6 steps x 4 independent shuffles), 1 rescale test + 4 exps
// per group. Running (m, sum, vacc) in registers; one barrier at the end.
// grid = B * NCHUNK = 2048 blocks, 256 threads
__global__ __launch_bounds__(256) void k_fused(
    const float* __restrict__ key, const float* __restrict__ value,
    float* __restrict__ ws) {
  int blk = blockIdx.x;
  int b = blk >> 7;         // / NCHUNK
  int chunk = blk & 127;
  int s0 = chunk * CHUNK;
  int t = threadIdx.x, lane = t & 63, wv = t >> 6;

  __shared__ float wm[4], wsum[4];
  __shared__ f4 wva[4][64];   // per-wave vacc (4 KB)

  f4 rv = ((const f4*)(ws + R_OFF + b * Dn))[lane] * kScale;  // fold scale into r
  float cb = ws[C_OFF + b] * kScale;
  const f4* kp = (const f4*)(key + ((size_t)b * Sn + s0) * Dn);
  const f4* vp = (const f4*)(value + ((size_t)b * Sn + s0) * Dn);

  float m = -1e30f, sum = 0.f;
  f4 vacc = {0.f, 0.f, 0.f, 0.f};
  int rbase = wv * 16;

  f4 kv0, kv1, kv2, kv3, vv0, vv1, vv2, vv3;
  kv0 = kp[(size_t)(rbase + 0) * 64 + lane];
  kv1 = kp[(size_t)(rbase + 1) * 64 + lane];
  kv2 = kp[(size_t)(rbase + 2) * 64 + lane];
  kv3 = kp[(size_t)(rbase + 3) * 64 + lane];
  vv0 = vp[(size_t)(rbase + 0) * 64 + lane];
  vv1 = vp[(size_t)(rbase + 1) * 64 + lane];
  vv2 = vp[(size_t)(rbase + 2) * 64 + lane];
  vv3 = vp[(size_t)(rbase + 3) * 64 + lane];

  #pragma unroll
  for (int g = 0; g < 4; ++g) {
    f4 kn0, kn1, kn2, kn3, vn0, vn1, vn2, vn3;
    if (g < 3) {                          // prefetch next group of 4 row-pairs
      int rn = rbase + (g + 1) * 4;
      kn0 = kp[(size_t)(rn + 0) * 64 + lane];
      kn1 = kp[(size_t)(rn + 1) * 64 + lane];
      kn2 = kp[(size_t)(rn + 2) * 64 + lane];
      kn3 = kp[(size_t)(rn + 3) * 64 + lane];
      vn0 = vp[(size_t)(rn + 0) * 64 + lane];
      vn1 = vp[(size_t)(rn + 1) * 64 + lane];
      vn2 = vp[(size_t)(rn + 2) * 64 + lane];
      vn3 = vp[(size_t)(rn + 3) * 64 + lane];
    }
    f4 d;
    d.x = kv0.x * rv.x + kv0.y * rv.y + kv0.z * rv.z + kv0.w * rv.w;
    d.y = kv1.x * rv.x + kv1.y * rv.y + kv1.z * rv.z + kv1.w * rv.w;
    d.z = kv2.x * rv.x + kv2.y * rv.y + kv2.z * rv.z + kv2.w * rv.w;
    d.w = kv3.x * rv.x + kv3.y * rv.y + kv3.z * rv.z + kv3.w * rv.w;
    #pragma unroll
    for (int off = 32; off; off >>= 1) {  // packed butterfly: 4 indep shuffles/step
      f4 o;
      o.x = __shfl_xor(d.x, off, 64);
      o.y = __shfl_xor(d.y, off, 64);
      o.z = __shfl_xor(d.z, off, 64);
      o.w = __shfl_xor(d.w, off, 64);
      d += o;
    }
    f4 s = d + cb;                        // 4 scores, identical in all lanes
    float sg = fmaxf(fmaxf(s.x, s.y), fmaxf(s.z, s.w));
    if (sg > m) {                         // wave-uniform, once per group at most
      float sc = __expf(m - sg);
      sum *= sc;
      vacc *= sc;
      m = sg;
    }
    float w0 = __expf(s.x - m), w1 = __expf(s.y - m);
    float w2 = __expf(s.z - m), w3 = __expf(s.w - m);
    sum += (w0 + w1) + (w2 + w3);
    vacc += w0 * vv0;
    vacc += w1 * vv1;
    vacc += w2 * vv2;
    vacc += w3 * vv3;
    kv0 = kn0; kv1 = kn1; kv2 = kn2; kv3 = kn3;
    vv0 = vn0; vv1 = vn1; vv2 = vn2; vv3 = vn3;
  }

  if (lane == 0) { wm[wv] = m; wsum[wv] = sum; }
  wva[wv][lane] = vacc;
  __syncthreads();

  float gm = fmaxf(fmaxf(wm[0], wm[1]), fmaxf(wm[2], wm[3]));
  float e0 = __expf(wm[0] - gm), e1 = __expf(wm[1] - gm);
  float e2 = __expf(wm[2] - gm), e3 = __expf(wm[3] - gm);
  const float* v0 = (const float*)&wva[0][0];
  const float* v1 = (const float*)&wva[1][0];
  const float* v2 = (const float*)&wva[2][0];
  const float* v3 = (const float*)&wva[3][0];
  float part = v0[t] * e0 + v1[t] * e1 + v2[t] * e2 + v3[t] * e3;
  ws[PART_OFF + ((size_t)b * NCHUNK + chunk) * Dn + t] = part;
  if (t == 0) {
    ws[M_OFF + b * NCHUNK + chunk] = gm;
    ws[SUM_OFF + b * NCHUNK + chunk] =
        wsum[0] * e0 + wsum[1] * e1 + wsum[2] * e2 + wsum[3] * e3;
  }
}

// ---------------------------------------------------------------------------
// K3: per (batch, 128-row slice): redundant LSE combine over 128 chunks
// (L2-resident) -> ctx = (u/denom)@Wv + bv, then nt-write 128 output rows.
// (unchanged from round 6/7)
__global__ __launch_bounds__(256) void k_out(
    const float* __restrict__ Wv, const float* __restrict__ bv,
    const float* __restrict__ ws, float* __restrict__ out) {
  int blk = blockIdx.x;
  int b = blk >> 6;          // 64 slices per batch
  int oc = blk & 63;
  int s0 = oc * OROWS;
  int t = threadIdx.x, lane = t & 63, wv = t >> 6;

  __shared__ float msh[NCHUNK];
  __shared__ float ssh[NCHUNK];
  __shared__ float e[NCHUNK];
  __shared__ float ush[Dn];
  __shared__ float ctx[Dn];

  if (t < NCHUNK) msh[t] = ws[M_OFF + b * NCHUNK + t];
  else            ssh[t - NCHUNK] = ws[SUM_OFF + b * NCHUNK + (t - NCHUNK)];
  __syncthreads();
  float gm = -1e30f;
  #pragma unroll 16
  for (int c = 0; c < NCHUNK; ++c) gm = fmaxf(gm, msh[c]);
  if (t < NCHUNK) e[t] = __expf(msh[t] - gm);
  __syncthreads();
  float denom = 0.f;
  #pragma unroll 16
  for (int c = 0; c < NCHUNK; ++c) denom += ssh[c] * e[c];
  float u = 0.f;
  #pragma unroll 16
  for (int c = 0; c < NCHUNK; ++c)
    u += ws[PART_OFF + ((size_t)b * NCHUNK + c) * Dn + t] * e[c];  // coalesced
  ush[t] = u / denom;
  __syncthreads();
  float acc = bv[t];
  #pragma unroll 16
  for (int o = 0; o < Dn; ++o) acc += ush[o] * Wv[o * Dn + t];  // coalesced
  ctx[t] = acc;
  __syncthreads();

  f4 val = ((const f4*)ctx)[lane];
  f4* op = (f4*)(out + ((size_t)b * Sn + s0) * Dn);
  #pragma unroll 8
  for (int it = 0; it < OROWS / 4; ++it) {
    int sl = wv + 4 * it;
    __builtin_nontemporal_store(val, &op[(size_t)sl * 64 + lane]);
  }
}

// ---------------------------------------------------------------------------
extern "C" void kernel_launch(void* const* d_in, const int* in_sizes, int n_in,
                              void* d_out, int out_size, void* d_ws, size_t ws_size,
                              hipStream_t stream) {
  const float* query = (const float*)d_in[0];
  const float* key   = (const float*)d_in[1];
  const float* value = (const float*)d_in[2];
  const float* Wq    = (const float*)d_in[3];
  const float* bq    = (const float*)d_in[4];
  const float* Wk    = (const float*)d_in[5];
  const float* bk    = (const float*)d_in[6];
  const float* Wv    = (const float*)d_in[7];
  const float* bv    = (const float*)d_in[8];
  float* out = (float*)d_out;
  float* ws  = (float*)d_ws;

  hipLaunchKernelGGL(k_qrc,   dim3(Bn),          dim3(256), 0, stream,
                     query, Wq, bq, Wk, bk, ws);
  hipLaunchKernelGGL(k_fused, dim3(Bn * NCHUNK), dim3(256), 0, stream,
                     key, value, ws);
  hipLaunchKernelGGL(k_out,   dim3(Bn * 64),     dim3(256), 0, stream,
                     Wv, bv, ws, out);
}

// Round 9
// 98.010 us; speedup vs baseline: 1.4408x; 1.0036x over previous
//
#include <hip/hip_runtime.h>

typedef float f4 __attribute__((ext_vector_type(4)));  // native vector for nt ld/st

// Problem constants
constexpr int Bn = 16;
constexpr int Sn = 8192;
constexpr int Dn = 256;             // D_MODEL = K_CH = OUT = 256
constexpr float kScale = 0.0625f;   // 1/sqrt(256)
constexpr int NCHUNK = 128;         // partial-chunks per batch (128 blocks/batch)
constexpr int OBLK   = 64;          // output blocks per batch

// Workspace layout (float offsets); ~530k floats = 2.1 MB
constexpr int R_OFF    = 0;                     // r[B][D] = Wk @ q
constexpr int C_OFF    = R_OFF + Bn * Dn;       // c[B]    = q . bk
constexpr int M_OFF    = C_OFF + 64;            // chunk max   [B][NCHUNK]
constexpr int SUM_OFF  = M_OFF + Bn * NCHUNK;   // chunk expsum[B][NCHUNK]
constexpr int PART_OFF = SUM_OFF + Bn * NCHUNK; // partials    [B][NCHUNK][D]

// ---------------------------------------------------------------------------
// K1: per-batch tiny GEMVs: q = query@Wq + bq ; r = Wk@q ; c = q.bk
// (unchanged)
__global__ __launch_bounds__(256) void k_qrc(
    const float* __restrict__ query, const float* __restrict__ Wq,
    const float* __restrict__ bq, const float* __restrict__ Wk,
    const float* __restrict__ bk, float* __restrict__ ws) {
  int b = blockIdx.x, t = threadIdx.x;
  __shared__ float qs[Dn];
  __shared__ float qh[Dn];
  __shared__ float red[256];
  qs[t] = query[b * Dn + t];
  __syncthreads();
  float acc = bq[t];
  #pragma unroll 32
  for (int d = 0; d < Dn; ++d) acc += qs[d] * Wq[d * Dn + t];  // coalesced over t
  qh[t] = acc;
  __syncthreads();
  float racc = 0.f;
  const f4* wkrow = (const f4*)(Wk + (size_t)t * Dn);
  const f4* qh4 = (const f4*)qh;
  #pragma unroll 16
  for (int o4 = 0; o4 < Dn / 4; ++o4) {
    f4 wv = wkrow[o4];
    f4 qv = qh4[o4];
    racc += wv.x * qv.x + wv.y * qv.y + wv.z * qv.z + wv.w * qv.w;
  }
  ws[R_OFF + b * Dn + t] = racc;
  red[t] = qh[t] * bk[t];
  __syncthreads();
  for (int off = 128; off; off >>= 1) {
    if (t < off) red[t] += red[t + off];
    __syncthreads();
  }
  if (t == 0) ws[C_OFF + b] = red[0];
}

// ---------------------------------------------------------------------------
// K2 (online softmax, INTERLEAVED row mapping): block (b, c) wave wv handles
// rows s = i*512 + (c*4 + wv), i = 0..15. At any instant the whole grid reads
// a few contiguous 512-row fronts instead of 4096 independent 64KB streams —
// DRAM row-buffer friendly. Online softmax is row-order invariant, so the
// partial/combine structure is unchanged.
// grid = B * NCHUNK = 2048 blocks, 256 threads
__global__ __launch_bounds__(256) void k_fused(
    const float* __restrict__ key, const float* __restrict__ value,
    float* __restrict__ ws) {
  int blk = blockIdx.x;
  int b = blk >> 7;         // / NCHUNK
  int c = blk & 127;
  int t = threadIdx.x, lane = t & 63, wv = t >> 6;
  int cw = c * 4 + wv;      // 0..511: this wave's position in the 512-row front

  __shared__ float wm[4], wsum[4];
  __shared__ f4 wva[4][64];   // per-wave vacc (4 KB)

  f4 rv = ((const f4*)(ws + R_OFF + b * Dn))[lane] * kScale;  // fold scale
  float cb = ws[C_OFF + b] * kScale;
  const f4* kp = (const f4*)(key + (size_t)b * Sn * Dn);
  const f4* vp = (const f4*)(value + (size_t)b * Sn * Dn);

  float m = -1e30f, sum = 0.f;
  f4 vacc = {0.f, 0.f, 0.f, 0.f};

  // Prologue: row-pair for i = 0
  f4 kv = kp[(size_t)cw * 64 + lane];
  f4 vv = vp[(size_t)cw * 64 + lane];

  #pragma unroll
  for (int i = 0; i < 16; ++i) {          // 16 rows per wave, 512 apart
    f4 kn, vn;
    if (i < 15) {                         // depth-1 prefetch
      size_t sn = (size_t)(i + 1) * 512 + cw;
      kn = kp[sn * 64 + lane];
      vn = vp[sn * 64 + lane];
    }
    float dot = kv.x * rv.x + kv.y * rv.y + kv.z * rv.z + kv.w * rv.w;
    #pragma unroll
    for (int off = 32; off; off >>= 1) dot += __shfl_xor(dot, off, 64);
    float s = dot + cb;                   // identical in all 64 lanes
    if (s > m) {                          // wave-uniform rescale, rare
      float sc = __expf(m - s);
      sum *= sc;
      vacc *= sc;
      m = s;
    }
    float w = __expf(s - m);
    sum += w;
    vacc += w * vv;
    kv = kn; vv = vn;
  }

  if (lane == 0) { wm[wv] = m; wsum[wv] = sum; }
  wva[wv][lane] = vacc;
  __syncthreads();

  float gm = fmaxf(fmaxf(wm[0], wm[1]), fmaxf(wm[2], wm[3]));
  float e0 = __expf(wm[0] - gm), e1 = __expf(wm[1] - gm);
  float e2 = __expf(wm[2] - gm), e3 = __expf(wm[3] - gm);
  const float* v0 = (const float*)&wva[0][0];
  const float* v1 = (const float*)&wva[1][0];
  const float* v2 = (const float*)&wva[2][0];
  const float* v3 = (const float*)&wva[3][0];
  float part = v0[t] * e0 + v1[t] * e1 + v2[t] * e2 + v3[t] * e3;
  ws[PART_OFF + ((size_t)b * NCHUNK + c) * Dn + t] = part;
  if (t == 0) {
    ws[M_OFF + b * NCHUNK + c] = gm;
    ws[SUM_OFF + b * NCHUNK + c] =
        wsum[0] * e0 + wsum[1] * e1 + wsum[2] * e2 + wsum[3] * e3;
  }
}

// ---------------------------------------------------------------------------
// K3: redundant LSE combine (L2-resident) -> ctx = (u/denom)@Wv + bv, then
// nt-write 128 rows with the same INTERLEAVED mapping: wave wv of block
// (b, oc) writes rows s = i*256 + (oc*4 + wv), i = 0..31.
// grid = B * OBLK = 1024 blocks, 256 threads
__global__ __launch_bounds__(256) void k_out(
    const float* __restrict__ Wv, const float* __restrict__ bv,
    const float* __restrict__ ws, float* __restrict__ out) {
  int blk = blockIdx.x;
  int b = blk >> 6;
  int oc = blk & 63;
  int t = threadIdx.x, lane = t & 63, wv = t >> 6;
  int cw = oc * 4 + wv;     // 0..255: position in the 256-row write front

  __shared__ float msh[NCHUNK];
  __shared__ float ssh[NCHUNK];
  __shared__ float e[NCHUNK];
  __shared__ float ush[Dn];
  __shared__ float ctx[Dn];

  if (t < NCHUNK) msh[t] = ws[M_OFF + b * NCHUNK + t];
  else            ssh[t - NCHUNK] = ws[SUM_OFF + b * NCHUNK + (t - NCHUNK)];
  __syncthreads();
  float gm = -1e30f;
  #pragma unroll 16
  for (int c = 0; c < NCHUNK; ++c) gm = fmaxf(gm, msh[c]);
  if (t < NCHUNK) e[t] = __expf(msh[t] - gm);
  __syncthreads();
  float denom = 0.f;
  #pragma unroll 16
  for (int c = 0; c < NCHUNK; ++c) denom += ssh[c] * e[c];
  float u = 0.f;
  #pragma unroll 16
  for (int c = 0; c < NCHUNK; ++c)
    u += ws[PART_OFF + ((size_t)b * NCHUNK + c) * Dn + t] * e[c];  // coalesced
  ush[t] = u / denom;
  __syncthreads();
  float acc = bv[t];
  #pragma unroll 16
  for (int o = 0; o < Dn; ++o) acc += ush[o] * Wv[o * Dn + t];  // coalesced
  ctx[t] = acc;
  __syncthreads();

  f4 val = ((const f4*)ctx)[lane];
  f4* op = (f4*)(out + (size_t)b * Sn * Dn);
  #pragma unroll 8
  for (int i = 0; i < 32; ++i) {
    size_t s = (size_t)i * 256 + cw;
    __builtin_nontemporal_store(val, &op[s * 64 + lane]);
  }
}

// ---------------------------------------------------------------------------
extern "C" void kernel_launch(void* const* d_in, const int* in_sizes, int n_in,
                              void* d_out, int out_size, void* d_ws, size_t ws_size,
                              hipStream_t stream) {
  const float* query = (const float*)d_in[0];
  const float* key   = (const float*)d_in[1];
  const float* value = (const float*)d_in[2];
  const float* Wq    = (const float*)d_in[3];
  const float* bq    = (const float*)d_in[4];
  const float* Wk    = (const float*)d_in[5];
  const float* bk    = (const float*)d_in[6];
  const float* Wv    = (const float*)d_in[7];
  const float* bv    = (const float*)d_in[8];
  float* out = (float*)d_out;
  float* ws  = (float*)d_ws;

  hipLaunchKernelGGL(k_qrc,   dim3(Bn),          dim3(256), 0, stream,
                     query, Wq, bq, Wk, bk, ws);
  hipLaunchKernelGGL(k_fused, dim3(Bn * NCHUNK), dim3(256), 0, stream,
                     key, value, ws);
  hipLaunchKernelGGL(k_out,   dim3(Bn * OBLK),   dim3(256), 0, stream,
                     Wv, bv, ws, out);
}

// Round 11
// 97.705 us; speedup vs baseline: 1.4453x; 1.0031x over previous
//
#include <hip/hip_runtime.h>

typedef float f4 __attribute__((ext_vector_type(4)));  // native vector for nt ld/st

// Problem constants
constexpr int Bn = 16;
constexpr int Sn = 8192;
constexpr int Dn = 256;             // D_MODEL = K_CH = OUT = 256
constexpr float kScale = 0.0625f;   // 1/sqrt(256)
constexpr int NCHUNK = 128;         // partial-chunks per batch (128 blocks/batch)
constexpr int OBLK   = 64;          // output blocks per batch

// Workspace layout (float offsets); ~530k floats = 2.1 MB
constexpr int R_OFF    = 0;                     // r[B][D] = Wk @ q
constexpr int C_OFF    = R_OFF + Bn * Dn;       // c[B]    = q . bk
constexpr int M_OFF    = C_OFF + 64;            // chunk max   [B][NCHUNK]
constexpr int SUM_OFF  = M_OFF + Bn * NCHUNK;   // chunk expsum[B][NCHUNK]
constexpr int PART_OFF = SUM_OFF + Bn * NCHUNK; // partials    [B][NCHUNK][D]

// ---------------------------------------------------------------------------
// Full-wave (64-lane) float sum with ZERO DS-pipe ops: 6 v_add_f32_dpp on the
// VALU pipe + one readlane broadcast. Lanes shifted in from out-of-range read
// 0 (bound_ctrl). After row_shr 1/2/4/8 each lane 15+16k holds its row-of-16
// sum; row_bcast15 then row_bcast31 fold the four rows into lane 63.
template <int CTRL>
__device__ __forceinline__ float dpp_term(float x) {
  return __builtin_bit_cast(float,
      __builtin_amdgcn_update_dpp(0, __builtin_bit_cast(int, x),
                                  CTRL, 0xf, 0xf, true));
}
__device__ __forceinline__ float wave_sum_dpp(float x) {
  x += dpp_term<0x111>(x);   // row_shr:1
  x += dpp_term<0x112>(x);   // row_shr:2
  x += dpp_term<0x114>(x);   // row_shr:4
  x += dpp_term<0x118>(x);   // row_shr:8
  x += dpp_term<0x142>(x);   // row_bcast:15
  x += dpp_term<0x143>(x);   // row_bcast:31
  return __builtin_bit_cast(float,
      __builtin_amdgcn_readlane(__builtin_bit_cast(int, x), 63));
}

// ---------------------------------------------------------------------------
// K1: per-batch tiny GEMVs: q = query@Wq + bq ; r = Wk@q ; c = q.bk
// (unchanged)
__global__ __launch_bounds__(256) void k_qrc(
    const float* __restrict__ query, const float* __restrict__ Wq,
    const float* __restrict__ bq, const float* __restrict__ Wk,
    const float* __restrict__ bk, float* __restrict__ ws) {
  int b = blockIdx.x, t = threadIdx.x;
  __shared__ float qs[Dn];
  __shared__ float qh[Dn];
  __shared__ float red[256];
  qs[t] = query[b * Dn + t];
  __syncthreads();
  float acc = bq[t];
  #pragma unroll 32
  for (int d = 0; d < Dn; ++d) acc += qs[d] * Wq[d * Dn + t];  // coalesced over t
  qh[t] = acc;
  __syncthreads();
  float racc = 0.f;
  const f4* wkrow = (const f4*)(Wk + (size_t)t * Dn);
  const f4* qh4 = (const f4*)qh;
  #pragma unroll 16
  for (int o4 = 0; o4 < Dn / 4; ++o4) {
    f4 wv = wkrow[o4];
    f4 qv = qh4[o4];
    racc += wv.x * qv.x + wv.y * qv.y + wv.z * qv.z + wv.w * qv.w;
  }
  ws[R_OFF + b * Dn + t] = racc;
  red[t] = qh[t] * bk[t];
  __syncthreads();
  for (int off = 128; off; off >>= 1) {
    if (t < off) red[t] += red[t + off];
    __syncthreads();
  }
  if (t == 0) ws[C_OFF + b] = red[0];
}

// ---------------------------------------------------------------------------
// K2 (online softmax, DPP reduce — zero DS ops in hot loop):
// block (b, c) wave wv handles rows s = i*512 + (c*4 + wv), i = 0..15.
// grid = B * NCHUNK = 2048 blocks, 256 threads
__global__ __launch_bounds__(256) void k_fused(
    const float* __restrict__ key, const float* __restrict__ value,
    float* __restrict__ ws) {
  int blk = blockIdx.x;
  int b = blk >> 7;         // / NCHUNK
  int c = blk & 127;
  int t = threadIdx.x, lane = t & 63, wv = t >> 6;
  int cw = c * 4 + wv;      // 0..511: position in the 512-row front

  __shared__ float wm[4], wsum[4];
  __shared__ f4 wva[4][64];   // per-wave vacc (4 KB)

  f4 rv = ((const f4*)(ws + R_OFF + b * Dn))[lane] * kScale;  // fold scale
  float cb = ws[C_OFF + b] * kScale;
  const f4* kp = (const f4*)(key + (size_t)b * Sn * Dn);
  const f4* vp = (const f4*)(value + (size_t)b * Sn * Dn);

  float m = -1e30f, sum = 0.f;
  f4 vacc = {0.f, 0.f, 0.f, 0.f};

  // Prologue: row-pair for i = 0
  f4 kv = kp[(size_t)cw * 64 + lane];
  f4 vv = vp[(size_t)cw * 64 + lane];

  #pragma unroll
  for (int i = 0; i < 16; ++i) {          // 16 rows per wave, 512 apart
    f4 kn, vn;
    if (i < 15) {                         // depth-1 prefetch
      size_t sn = (size_t)(i + 1) * 512 + cw;
      kn = kp[sn * 64 + lane];
      vn = vp[sn * 64 + lane];
    }
    float pd = kv.x * rv.x + kv.y * rv.y + kv.z * rv.z + kv.w * rv.w;
    float s = wave_sum_dpp(pd) + cb;      // uniform in all lanes
    if (s > m) {                          // wave-uniform branch, rare
      float sc = __expf(m - s);
      sum *= sc;
      vacc *= sc;
      m = s;
    }
    float w = __expf(s - m);
    sum += w;
    vacc += w * vv;
    kv = kn; vv = vn;
  }

  if (lane == 0) { wm[wv] = m; wsum[wv] = sum; }
  wva[wv][lane] = vacc;
  __syncthreads();

  float gm = fmaxf(fmaxf(wm[0], wm[1]), fmaxf(wm[2], wm[3]));
  float e0 = __expf(wm[0] - gm), e1 = __expf(wm[1] - gm);
  float e2 = __expf(wm[2] - gm), e3 = __expf(wm[3] - gm);
  const float* v0 = (const float*)&wva[0][0];
  const float* v1 = (const float*)&wva[1][0];
  const float* v2 = (const float*)&wva[2][0];
  const float* v3 = (const float*)&wva[3][0];
  float part = v0[t] * e0 + v1[t] * e1 + v2[t] * e2 + v3[t] * e3;
  ws[PART_OFF + ((size_t)b * NCHUNK + c) * Dn + t] = part;
  if (t == 0) {
    ws[M_OFF + b * NCHUNK + c] = gm;
    ws[SUM_OFF + b * NCHUNK + c] =
        wsum[0] * e0 + wsum[1] * e1 + wsum[2] * e2 + wsum[3] * e3;
  }
}

// ---------------------------------------------------------------------------
// K3: redundant LSE combine (L2-resident) -> ctx = (u/denom)@Wv + bv, then
// nt-write 128 rows, interleaved mapping. (unchanged)
// grid = B * OBLK = 1024 blocks, 256 threads
__global__ __launch_bounds__(256) void k_out(
    const float* __restrict__ Wv, const float* __restrict__ bv,
    const float* __restrict__ ws, float* __restrict__ out) {
  int blk = blockIdx.x;
  int b = blk >> 6;
  int oc = blk & 63;
  int t = threadIdx.x, lane = t & 63, wv = t >> 6;
  int cw = oc * 4 + wv;     // 0..255: position in the 256-row write front

  __shared__ float msh[NCHUNK];
  __shared__ float ssh[NCHUNK];
  __shared__ float e[NCHUNK];
  __shared__ float ush[Dn];
  __shared__ float ctx[Dn];

  if (t < NCHUNK) msh[t] = ws[M_OFF + b * NCHUNK + t];
  else            ssh[t - NCHUNK] = ws[SUM_OFF + b * NCHUNK + (t - NCHUNK)];
  __syncthreads();
  float gm = -1e30f;
  #pragma unroll 16
  for (int c = 0; c < NCHUNK; ++c) gm = fmaxf(gm, msh[c]);
  if (t < NCHUNK) e[t] = __expf(msh[t] - gm);
  __syncthreads();
  float denom = 0.f;
  #pragma unroll 16
  for (int c = 0; c < NCHUNK; ++c) denom += ssh[c] * e[c];
  float u = 0.f;
  #pragma unroll 16
  for (int c = 0; c < NCHUNK; ++c)
    u += ws[PART_OFF + ((size_t)b * NCHUNK + c) * Dn + t] * e[c];  // coalesced
  ush[t] = u / denom;
  __syncthreads();
  float acc = bv[t];
  #pragma unroll 16
  for (int o = 0; o < Dn; ++o) acc += ush[o] * Wv[o * Dn + t];  // coalesced
  ctx[t] = acc;
  __syncthreads();

  f4 val = ((const f4*)ctx)[lane];
  f4* op = (f4*)(out + (size_t)b * Sn * Dn);
  #pragma unroll 8
  for (int i = 0; i < 32; ++i) {
    size_t s = (size_t)i * 256 + cw;
    __builtin_nontemporal_store(val, &op[s * 64 + lane]);
  }
}

// ---------------------------------------------------------------------------
extern "C" void kernel_launch(void* const* d_in, const int* in_sizes, int n_in,
                              void* d_out, int out_size, void* d_ws, size_t ws_size,
                              hipStream_t stream) {
  const float* query = (const float*)d_in[0];
  const float* key   = (const float*)d_in[1];
  const float* value = (const float*)d_in[2];
  const float* Wq    = (const float*)d_in[3];
  const float* bq    = (const float*)d_in[4];
  const float* Wk    = (const float*)d_in[5];
  const float* bk    = (const float*)d_in[6];
  const float* Wv    = (const float*)d_in[7];
  const float* bv    = (const float*)d_in[8];
  float* out = (float*)d_out;
  float* ws  = (float*)d_ws;

  hipLaunchKernelGGL(k_qrc,   dim3(Bn),          dim3(256), 0, stream,
                     query, Wq, bq, Wk, bk, ws);
  hipLaunchKernelGGL(k_fused, dim3(Bn * NCHUNK), dim3(256), 0, stream,
                     key, value, ws);
  hipLaunchKernelGGL(k_out,   dim3(Bn * OBLK),   dim3(256), 0, stream,
                     Wv, bv, ws, out);
}